// Round 7
// baseline (169.887 us; speedup 1.0000x reference)
//
#include <hip/hip_runtime.h>

// ============================================================================
// LeViT attention, MI355X. I/O tensors are FLOAT32 (per reference).
// b=2, C=256, H=W=56, n=3136, heads=8, kd=16, dh=64.
// v16 = v15's packed xtw/qkv/proj (unchanged) + attn occupancy/VALU fix:
//   - qt=1: grid (16 bh, 196 q-tiles), 3136 one-wave blocks (3.06 waves/SIMD
//     vs 1.5) -> MFMA/trans/VALU pipes overlap across waves.
//   - P-pack via v_cvt_pk_bf16_f32 (8 instr vs ~44 manual VALU per chunk).
//   - s_setprio(1) around PV MFMA cluster (T5, proven on 1-wave attn).
// Generic pack for M[R][C] consumed as 16-row MFMA frags:
//   pk[((rt*nkc + kc)*64 + lane)*8 + j] = M[rt*16+(lane&15)][kc*32+(lane>>4)*8+j]
// ws (u16 elems): qws 802816 | kws 802816 | vpk 3211264 | R 3211264
//   (R = xpk during xtw/qkv, opk from attn on) | wqpk 32768 | wkpk 32768 |
//   wvpk 131072 | wppk 131072   => 16,711,680 B
// MFMA 16x16x32_bf16: A[m=l15][k=quad*8+j]; B[k=quad*8+j][n=l15];
// C/D: col=l15, row=quad*4+reg.
// vpk layout (proven v13): vpk[((bh*49+c)*8 + (c32*4+dt))*512 + lane*8 + j]
//   = V[bh][d=dt*16+(lane&15)][key=c*64+c32*32+(j>>2)*16+(lane>>4)*4+(j&3)]
// ============================================================================

typedef short  s16x8 __attribute__((ext_vector_type(8)));
typedef float  f32x4 __attribute__((ext_vector_type(4)));
typedef int    i32x4 __attribute__((ext_vector_type(4)));
typedef unsigned short u16;
typedef unsigned short u16x4 __attribute__((ext_vector_type(4)));

__device__ __forceinline__ u16 f2bf(float f) {   // RNE
    unsigned u = __builtin_bit_cast(unsigned, f);
    u += 0x7FFF + ((u >> 16) & 1);
    return (u16)(u >> 16);
}
__device__ __forceinline__ f32x4 mfma32(s16x8 a, s16x8 b, f32x4 c) {
    return __builtin_amdgcn_mfma_f32_16x16x32_bf16(a, b, c, 0, 0, 0);
}
__device__ __forceinline__ int cvtpk(float lo, float hi) { // 2xf32 -> 2xbf16
    int r;
    asm("v_cvt_pk_bf16_f32 %0, %1, %2" : "=v"(r) : "v"(lo), "v"(hi));
    return r;
}

// ---------------------------------------------------------------------------
// xtw: z<2 -> x fp32 -> xpk (x_t in packed fragment order); z==2 -> pack all
// weights W'=s*W into fragment order. grid (49,4,3), 256 thr.
// ---------------------------------------------------------------------------
__global__ __launch_bounds__(256) void xtw_kernel(
    const float* __restrict__ x, u16* __restrict__ xpk,
    const float* __restrict__ wq, const float* __restrict__ sq,
    const float* __restrict__ wk, const float* __restrict__ sk,
    const float* __restrict__ wv, const float* __restrict__ sv,
    const float* __restrict__ wp, const float* __restrict__ sp,
    u16* __restrict__ wqpk, u16* __restrict__ wkpk,
    u16* __restrict__ wvpk, u16* __restrict__ wppk)
{
    const int t = threadIdx.x;
    if (blockIdx.z == 2) {
        // weight pack: chunk ch -> (rt, kc, lane); dst[ch*8+j] holds
        // W'[rt*16+l15][kc*32+q*8+j].  wq 4096 | wk 4096 | wv 16384 | wp 16384
        int ch = (blockIdx.y * 49 + blockIdx.x) * 256 + t;
        const float *W, *S; u16* dst; int nkc;
        if (ch < 4096)        { W = wq; S = sq; dst = wqpk; nkc = 8; }
        else if (ch < 8192)   { W = wk; S = sk; dst = wkpk; nkc = 8;  ch -= 4096; }
        else if (ch < 24576)  { W = wv; S = sv; dst = wvpk; nkc = 8;  ch -= 8192; }
        else if (ch < 40960)  { W = wp; S = sp; dst = wppk; nkc = 16; ch -= 24576; }
        else return;
        const int lane = ch & 63, kc = (ch >> 6) % nkc, rt = (ch >> 6) / nkc;
        const int l15 = lane & 15, q = lane >> 4;
        const int row = rt * 16 + l15, C = nkc * 32;
        const float sc = S[row];
        const float* src = &W[row * C + kc * 32 + q * 8];
        s16x8 o;
        #pragma unroll
        for (int j = 0; j < 8; j++) o[j] = (short)f2bf(src[j] * sc);
        *(s16x8*)&dst[ch * 8] = o;
        return;
    }
    const int b = blockIdx.z, c0 = blockIdx.y * 64, n0 = blockIdx.x * 64;
    __shared__ float lds[64][65];
    const int nl = t & 63, cl = t >> 6;
    #pragma unroll
    for (int i = 0; i < 16; i++) {
        const int c = cl + i * 4;
        lds[c][nl] = x[(b * 256 + c0 + c) * 3136 + n0 + nl];
    }
    __syncthreads();
    // packed write: idx -> (t16l 0..3, kc8l 0..1, lane); value =
    // x_t[n0+t16l*16+l15][c0+kc8l*32+q*8+j] = lds[kc8l*32+q*8+j][t16l*16+l15]
    #pragma unroll
    for (int rep = 0; rep < 2; rep++) {
        const int idx = rep * 256 + t;
        const int t16l = idx >> 7, kc8l = (idx >> 6) & 1, lane = idx & 63;
        const int l15 = lane & 15, q = lane >> 4;
        s16x8 o;
        #pragma unroll
        for (int j = 0; j < 8; j++)
            o[j] = (short)f2bf(lds[kc8l * 32 + q * 8 + j][t16l * 16 + l15]);
        const int tg = (n0 >> 4) + t16l, kg = (c0 >> 5) + kc8l;
        *(s16x8*)&xpk[(((b * 196 + tg) * 8 + kg) * 64 + lane) * 8] = o;
    }
}

// ---------------------------------------------------------------------------
// QKV MFMA GEMM: ALL loads fully coalesced from packed layouts.
// grid (49 n-tiles, 12 rt, 2 b). rt 0..3: q/k (token-major store, q scaled
// by log2e); rt 4..11: v (stored packed for attn, proven v13 layout).
// ---------------------------------------------------------------------------
__global__ __launch_bounds__(256, 4) void qkv_kernel(
    const u16* __restrict__ xpk,
    const u16* __restrict__ wqpk, const u16* __restrict__ wkpk, const u16* __restrict__ wvpk,
    const float* __restrict__ bq, const float* __restrict__ bk, const float* __restrict__ bv,
    u16* __restrict__ qws, u16* __restrict__ kws, u16* __restrict__ vpk)
{
    const int b = blockIdx.z, rt = blockIdx.y, n0 = blockIdx.x * 64;
    const int t = threadIdx.x, wave = t >> 6, lane = t & 63;
    const int l15 = lane & 15, quad = lane >> 4;
    const f32x4 z = {0.f, 0.f, 0.f, 0.f};

    if (rt < 4) {
        const u16* wb      = (rt < 2) ? wqpk : wkpk;
        const float* bias  = (rt < 2) ? bq : bk;
        u16* dst           = (rt < 2) ? qws : kws;
        const float qs     = (rt < 2) ? 1.44269504088896f : 1.0f;  // fold log2e
        const int och0 = (rt & 1) * 64;
        const int m0   = n0 + wave * 16;
        const int m_t  = blockIdx.x * 4 + wave;
        s16x8 a8[8];
        #pragma unroll
        for (int kc8 = 0; kc8 < 8; kc8++)
            a8[kc8] = *(const s16x8*)&xpk[(((b * 196 + m_t) * 8 + kc8) * 64 + lane) * 8];
        f32x4 acc[4] = {z, z, z, z};
        #pragma unroll
        for (int kc8 = 0; kc8 < 8; kc8++) {
            #pragma unroll
            for (int f = 0; f < 4; f++) {
                s16x8 bf = *(const s16x8*)&wb[((((rt & 1) * 4 + f) * 8 + kc8) * 64 + lane) * 8];
                acc[f] = mfma32(a8[kc8], bf, acc[f]);
            }
        }
        #pragma unroll
        for (int f = 0; f < 4; f++) {
            const int och = och0 + f * 16 + l15;
            const float bi = bias[och];
            const int h = och >> 4;
            #pragma unroll
            for (int r = 0; r < 4; r++) {
                const int tok = m0 + quad * 4 + r;
                dst[((b * 8 + h) * 3136 + tok) * 16 + l15] = f2bf((acc[f][r] + bi) * qs);
            }
        }
    } else {
        const int h    = rt - 4;
        const int och0 = h * 64 + wave * 16;
        s16x8 a8[8];
        #pragma unroll
        for (int kc8 = 0; kc8 < 8; kc8++)
            a8[kc8] = *(const s16x8*)&wvpk[(((h * 4 + wave) * 8 + kc8) * 64 + lane) * 8];
        f32x4 acc[4] = {z, z, z, z};
        #pragma unroll
        for (int kc8 = 0; kc8 < 8; kc8++) {
            #pragma unroll
            for (int f = 0; f < 4; f++) {
                s16x8 bf = *(const s16x8*)&xpk[(((b * 196 + blockIdx.x * 4 + f) * 8 + kc8) * 64 + lane) * 8];
                acc[f] = mfma32(a8[kc8], bf, acc[f]);
            }
        }
        // Packed V write (proven v13): value (d=wave*16+quad*4+r,
        // key=c*64+f*16+l15) -> block (c32=f>>1, dt=wave),
        // lane=(l15>>2)*16+quad*4+r, j=(f&1)*4+(l15&3)
        u16* vdst = &vpk[(((b * 8 + h) * 49 + blockIdx.x) * 8) * 512];
        #pragma unroll
        for (int r = 0; r < 4; r++) {
            const float bi = bv[och0 + quad * 4 + r];
            const int lane_r8 = ((l15 >> 2) * 16 + quad * 4 + r) * 8;
            #pragma unroll
            for (int f = 0; f < 4; f++) {
                const int idx = ((f >> 1) * 4 + wave) * 512 + lane_r8 + (f & 1) * 4 + (l15 & 3);
                vdst[idx] = f2bf(acc[f][r] + bi);
            }
        }
    }
}

// ---------------------------------------------------------------------------
// Flash attention v16: no LDS/barriers; packed-V 1024B loads, K 512B bursts;
// 1 q-tile per wave, 1-wave blocks -> grid (16 bh, 196) = 3136 blocks
// (3.06 waves/SIMD; pipes overlap across waves). A/B register prefetch.
// P-pack via v_cvt_pk_bf16_f32; setprio(1) around PV MFMA cluster.
// Epilogue writes o PACKED for proj. 64 thr.
// ---------------------------------------------------------------------------
__global__ __launch_bounds__(64) void attn_kernel(
    const u16* __restrict__ qws, const u16* __restrict__ kws,
    const u16* __restrict__ vpk, u16* __restrict__ opk)
{
    const int bh   = blockIdx.x;                 // x fastest -> XCD = bh%8
    const int nb   = blockIdx.y * 16;            // this wave's q-tile
    const int lane = threadIdx.x;
    const int l15  = lane & 15, quad = lane >> 4;

    // Q fragment (B-op): B[k=d=quad*8+j][n=query=l15]; zero for d>=16
    s16x8 aq = {0, 0, 0, 0, 0, 0, 0, 0};
    if (quad < 2)
        aq = *(const s16x8*)&qws[(bh * 3136 + nb + l15) * 16 + quad * 8];
    s16x8 ones;
    #pragma unroll
    for (int i = 0; i < 8; i++) ones[i] = (short)0x3F80;   // bf16 1.0

    // K frag: A[m=key=l15][k=quad*8+j]; quads 2,3 duplicate 0,1 (B=0 there)
    const u16* krow = &kws[(bh * 3136 + l15) * 16 + (quad & 1) * 8];
    const u16* vb   = &vpk[bh * 49 * 4096 + lane * 8];

    f32x4 acc[4], acc5;
    #pragma unroll
    for (int dt = 0; dt < 4; dt++) acc[dt] = (f32x4){0.f, 0.f, 0.f, 0.f};
    acc5 = (f32x4){0.f, 0.f, 0.f, 0.f};
    const f32x4 z = {0.f, 0.f, 0.f, 0.f};

    s16x8 kfA[4], vfA[8], kfB[4], vfB[8];
    auto loadK = [&](s16x8* kf, int c) {
        #pragma unroll
        for (int ii = 0; ii < 4; ii++)
            kf[ii] = *(const s16x8*)&krow[(c * 64 + ii * 16) * 16];
    };
    auto loadV = [&](s16x8* vf, int c) {
        #pragma unroll
        for (int i = 0; i < 8; i++)
            vf[i] = *(const s16x8*)&vb[(c * 8 + i) * 512];
    };
    auto compute = [&](const s16x8* kf, const s16x8* vf) {
        f32x4 s[4];
        #pragma unroll
        for (int ii = 0; ii < 4; ii++) s[ii] = mfma32(kf[ii], aq, z);
        // exp2 then pack pairs with v_cvt_pk_bf16_f32:
        // pf[c32] words: w0=pk(e[2c32][0],e[2c32][1]) w1=pk(e[2c32][2],[3])
        //                w2=pk(e[2c32+1][0],[1])      w3=pk(e[2c32+1][2],[3])
        float e[4][4];
        #pragma unroll
        for (int ii = 0; ii < 4; ii++)
            #pragma unroll
            for (int r = 0; r < 4; r++)
                e[ii][r] = __builtin_amdgcn_exp2f(s[ii][r]);
        s16x8 pf[2];
        #pragma unroll
        for (int c32 = 0; c32 < 2; c32++) {
            i32x4 pk;
            pk[0] = cvtpk(e[2 * c32][0],     e[2 * c32][1]);
            pk[1] = cvtpk(e[2 * c32][2],     e[2 * c32][3]);
            pk[2] = cvtpk(e[2 * c32 + 1][0], e[2 * c32 + 1][1]);
            pk[3] = cvtpk(e[2 * c32 + 1][2], e[2 * c32 + 1][3]);
            pf[c32] = __builtin_bit_cast(s16x8, pk);
        }
        __builtin_amdgcn_s_setprio(1);
        #pragma unroll
        for (int c32 = 0; c32 < 2; c32++) {
            #pragma unroll
            for (int dt = 0; dt < 4; dt++)
                acc[dt] = mfma32(vf[c32 * 4 + dt], pf[c32], acc[dt]);
            acc5 = mfma32(ones, pf[c32], acc5);
        }
        __builtin_amdgcn_s_setprio(0);
    };

    loadK(kfA, 0); loadV(vfA, 0);
    #pragma unroll 1
    for (int c = 0; c < 49; c += 2) {
        if (c + 1 < 49) { loadK(kfB, c + 1); loadV(vfB, c + 1); }
        compute(kfA, vfA);
        if (c + 2 < 49) { loadK(kfA, c + 2); loadV(vfA, c + 2); }
        if (c + 1 < 49) compute(kfB, vfB);
    }

    // ---- epilogue: write o PACKED for proj (vectorized).
    // value (tok = nb+l15, ch = h*64 + dt*16 + quad*4 + r) lands at
    // opk[((bq*196+tt)*16 + h*2+(dt>>1))*512
    //     + (((dt&1)*2+(quad>>1))*16 + l15)*8 + (quad&1)*4 + r]
    const int bq_ = bh >> 3, h = bh & 7;
    const float inv = 1.0f / acc5[0];            // rowsum for query l15
    u16* ob = &opk[((bq_ * 196 + blockIdx.y) * 16) * 512];
    #pragma unroll
    for (int dt = 0; dt < 4; dt++) {
        u16x4 o4;
        #pragma unroll
        for (int r = 0; r < 4; r++) o4[r] = f2bf(acc[dt][r] * inv);
        *(u16x4*)&ob[(h * 2 + (dt >> 1)) * 512 +
                     (((dt & 1) * 2 + (quad >> 1)) * 16 + l15) * 8 +
                     (quad & 1) * 4] = o4;
    }
}

// ---------------------------------------------------------------------------
// Output projection: ALL loads coalesced from packed layouts. grid (98,4,2).
// A = wppk [256][512] packed, B = opk; C[och][token] -> fp32 out.
// ---------------------------------------------------------------------------
__global__ __launch_bounds__(256, 4) void proj_kernel(
    const u16* __restrict__ opk, const u16* __restrict__ wppk,
    const float* __restrict__ bp, float* __restrict__ out)
{
    const int b = blockIdx.z, n0 = blockIdx.x * 32;
    const int och0 = blockIdx.y * 64 + (threadIdx.x >> 6) * 16;
    const int lane = threadIdx.x & 63;
    const int l15 = lane & 15, quad = lane >> 4;
    const f32x4 z = {0.f, 0.f, 0.f, 0.f};

    const int och_t = blockIdx.y * 4 + (threadIdx.x >> 6);
    s16x8 a8[16];
    #pragma unroll
    for (int kc = 0; kc < 16; kc++)
        a8[kc] = *(const s16x8*)&wppk[((och_t * 16 + kc) * 64 + lane) * 8];
    f32x4 acc[2] = {z, z};
    #pragma unroll
    for (int kc = 0; kc < 16; kc++) {
        #pragma unroll
        for (int f = 0; f < 2; f++) {
            s16x8 bf = *(const s16x8*)&opk[(((b * 196 + blockIdx.x * 2 + f) * 16 + kc) * 64 + lane) * 8];
            acc[f] = mfma32(a8[kc], bf, acc[f]);
        }
    }
    #pragma unroll
    for (int r = 0; r < 4; r++) {
        const int och = och0 + quad * 4 + r;
        const float bi = bp[och];
        #pragma unroll
        for (int f = 0; f < 2; f++)
            out[(b * 256 + och) * 3136 + n0 + f * 16 + l15] = acc[f][r] + bi;
    }
}

// ---------------------------------------------------------------------------
extern "C" void kernel_launch(void* const* d_in, const int* in_sizes, int n_in,
                              void* d_out, int out_size, void* d_ws, size_t ws_size,
                              hipStream_t stream) {
    const float* x  = (const float*)d_in[0];
    const float* wq = (const float*)d_in[1];
    const float* sq = (const float*)d_in[2];
    const float* bq = (const float*)d_in[3];
    const float* wk = (const float*)d_in[4];
    const float* sk = (const float*)d_in[5];
    const float* bk = (const float*)d_in[6];
    const float* wv = (const float*)d_in[7];
    const float* sv = (const float*)d_in[8];
    const float* bv = (const float*)d_in[9];
    const float* wp = (const float*)d_in[10];
    const float* sp = (const float*)d_in[11];
    const float* bp = (const float*)d_in[12];
    float* out = (float*)d_out;

    u16* qws  = (u16*)d_ws;                // 802816
    u16* kws  = qws + 802816;              // 802816
    u16* vpk  = kws + 802816;              // 3211264 (packed V)
    u16* R    = vpk + 3211264;             // 3211264 (xpk then opk, overlaid)
    u16* xpk  = R;
    u16* opk  = R;
    u16* wqpk = R + 3211264;               // 32768
    u16* wkpk = wqpk + 32768;              // 32768
    u16* wvpk = wkpk + 32768;              // 131072
    u16* wppk = wvpk + 131072;             // 131072  (total 16,711,680 B)

    xtw_kernel<<<dim3(49, 4, 3), 256, 0, stream>>>(x, xpk, wq, sq, wk, sk,
                                                   wv, sv, wp, sp,
                                                   wqpk, wkpk, wvpk, wppk);
    qkv_kernel<<<dim3(49, 12, 2), 256, 0, stream>>>(xpk, wqpk, wkpk, wvpk,
                                                    bq, bk, bv, qws, kws, vpk);
    attn_kernel<<<dim3(16, 196), 64, 0, stream>>>(qws, kws, vpk, opk);
    proj_kernel<<<dim3(98, 4, 2), 256, 0, stream>>>(opk, wppk, bp, out);
}

// Round 8
// 149.150 us; speedup vs baseline: 1.1390x; 1.1390x over previous
//
#include <hip/hip_runtime.h>

// ============================================================================
// LeViT attention, MI355X. I/O tensors are FLOAT32 (per reference).
// b=2, C=256, H=W=56, n=3136, heads=8, kd=16, dh=64.
// v17 = v15 (proven 152us total: packed xtw/qkv/proj + attn qt=2 schedule at
// 52.4us) + cvt_pk P-pack (proven in v16: VALU -12%, VGPR -12, same absmax)
// + setprio(1) around PV MFMA. attn stays qt=2 (K/V amortization proven
// essential: qt=1 in v16 doubled L2 stream -> 73us).
// Generic pack for M[R][C] consumed as 16-row MFMA frags:
//   pk[((rt*nkc + kc)*64 + lane)*8 + j] = M[rt*16+(lane&15)][kc*32+(lane>>4)*8+j]
// ws (u16 elems): qws 802816 | kws 802816 | vpk 3211264 | R 3211264
//   (R = xpk during xtw/qkv, opk from attn on) | wqpk 32768 | wkpk 32768 |
//   wvpk 131072 | wppk 131072   => 16,711,680 B
// MFMA 16x16x32_bf16: A[m=l15][k=quad*8+j]; B[k=quad*8+j][n=l15];
// C/D: col=l15, row=quad*4+reg.
// vpk layout (proven v13): vpk[((bh*49+c)*8 + (c32*4+dt))*512 + lane*8 + j]
//   = V[bh][d=dt*16+(lane&15)][key=c*64+c32*32+(j>>2)*16+(lane>>4)*4+(j&3)]
// ============================================================================

typedef short  s16x8 __attribute__((ext_vector_type(8)));
typedef float  f32x4 __attribute__((ext_vector_type(4)));
typedef int    i32x4 __attribute__((ext_vector_type(4)));
typedef unsigned short u16;
typedef unsigned short u16x4 __attribute__((ext_vector_type(4)));

__device__ __forceinline__ u16 f2bf(float f) {   // RNE
    unsigned u = __builtin_bit_cast(unsigned, f);
    u += 0x7FFF + ((u >> 16) & 1);
    return (u16)(u >> 16);
}
__device__ __forceinline__ f32x4 mfma32(s16x8 a, s16x8 b, f32x4 c) {
    return __builtin_amdgcn_mfma_f32_16x16x32_bf16(a, b, c, 0, 0, 0);
}
__device__ __forceinline__ int cvtpk(float lo, float hi) { // 2xf32 -> 2xbf16
    int r;
    asm("v_cvt_pk_bf16_f32 %0, %1, %2" : "=v"(r) : "v"(lo), "v"(hi));
    return r;
}

// ---------------------------------------------------------------------------
// xtw: z<2 -> x fp32 -> xpk (x_t in packed fragment order); z==2 -> pack all
// weights W'=s*W into fragment order. grid (49,4,3), 256 thr.
// ---------------------------------------------------------------------------
__global__ __launch_bounds__(256) void xtw_kernel(
    const float* __restrict__ x, u16* __restrict__ xpk,
    const float* __restrict__ wq, const float* __restrict__ sq,
    const float* __restrict__ wk, const float* __restrict__ sk,
    const float* __restrict__ wv, const float* __restrict__ sv,
    const float* __restrict__ wp, const float* __restrict__ sp,
    u16* __restrict__ wqpk, u16* __restrict__ wkpk,
    u16* __restrict__ wvpk, u16* __restrict__ wppk)
{
    const int t = threadIdx.x;
    if (blockIdx.z == 2) {
        // weight pack: chunk ch -> (rt, kc, lane); dst[ch*8+j] holds
        // W'[rt*16+l15][kc*32+q*8+j].  wq 4096 | wk 4096 | wv 16384 | wp 16384
        int ch = (blockIdx.y * 49 + blockIdx.x) * 256 + t;
        const float *W, *S; u16* dst; int nkc;
        if (ch < 4096)        { W = wq; S = sq; dst = wqpk; nkc = 8; }
        else if (ch < 8192)   { W = wk; S = sk; dst = wkpk; nkc = 8;  ch -= 4096; }
        else if (ch < 24576)  { W = wv; S = sv; dst = wvpk; nkc = 8;  ch -= 8192; }
        else if (ch < 40960)  { W = wp; S = sp; dst = wppk; nkc = 16; ch -= 24576; }
        else return;
        const int lane = ch & 63, kc = (ch >> 6) % nkc, rt = (ch >> 6) / nkc;
        const int l15 = lane & 15, q = lane >> 4;
        const int row = rt * 16 + l15, C = nkc * 32;
        const float sc = S[row];
        const float* src = &W[row * C + kc * 32 + q * 8];
        s16x8 o;
        #pragma unroll
        for (int j = 0; j < 8; j++) o[j] = (short)f2bf(src[j] * sc);
        *(s16x8*)&dst[ch * 8] = o;
        return;
    }
    const int b = blockIdx.z, c0 = blockIdx.y * 64, n0 = blockIdx.x * 64;
    __shared__ float lds[64][65];
    const int nl = t & 63, cl = t >> 6;
    #pragma unroll
    for (int i = 0; i < 16; i++) {
        const int c = cl + i * 4;
        lds[c][nl] = x[(b * 256 + c0 + c) * 3136 + n0 + nl];
    }
    __syncthreads();
    // packed write: idx -> (t16l 0..3, kc8l 0..1, lane); value =
    // x_t[n0+t16l*16+l15][c0+kc8l*32+q*8+j] = lds[kc8l*32+q*8+j][t16l*16+l15]
    #pragma unroll
    for (int rep = 0; rep < 2; rep++) {
        const int idx = rep * 256 + t;
        const int t16l = idx >> 7, kc8l = (idx >> 6) & 1, lane = idx & 63;
        const int l15 = lane & 15, q = lane >> 4;
        s16x8 o;
        #pragma unroll
        for (int j = 0; j < 8; j++)
            o[j] = (short)f2bf(lds[kc8l * 32 + q * 8 + j][t16l * 16 + l15]);
        const int tg = (n0 >> 4) + t16l, kg = (c0 >> 5) + kc8l;
        *(s16x8*)&xpk[(((b * 196 + tg) * 8 + kg) * 64 + lane) * 8] = o;
    }
}

// ---------------------------------------------------------------------------
// QKV MFMA GEMM: ALL loads fully coalesced from packed layouts.
// grid (49 n-tiles, 12 rt, 2 b). rt 0..3: q/k (token-major store, q scaled
// by log2e); rt 4..11: v (stored packed for attn, proven v13 layout).
// ---------------------------------------------------------------------------
__global__ __launch_bounds__(256, 4) void qkv_kernel(
    const u16* __restrict__ xpk,
    const u16* __restrict__ wqpk, const u16* __restrict__ wkpk, const u16* __restrict__ wvpk,
    const float* __restrict__ bq, const float* __restrict__ bk, const float* __restrict__ bv,
    u16* __restrict__ qws, u16* __restrict__ kws, u16* __restrict__ vpk)
{
    const int b = blockIdx.z, rt = blockIdx.y, n0 = blockIdx.x * 64;
    const int t = threadIdx.x, wave = t >> 6, lane = t & 63;
    const int l15 = lane & 15, quad = lane >> 4;
    const f32x4 z = {0.f, 0.f, 0.f, 0.f};

    if (rt < 4) {
        const u16* wb      = (rt < 2) ? wqpk : wkpk;
        const float* bias  = (rt < 2) ? bq : bk;
        u16* dst           = (rt < 2) ? qws : kws;
        const float qs     = (rt < 2) ? 1.44269504088896f : 1.0f;  // fold log2e
        const int och0 = (rt & 1) * 64;
        const int m0   = n0 + wave * 16;
        const int m_t  = blockIdx.x * 4 + wave;
        s16x8 a8[8];
        #pragma unroll
        for (int kc8 = 0; kc8 < 8; kc8++)
            a8[kc8] = *(const s16x8*)&xpk[(((b * 196 + m_t) * 8 + kc8) * 64 + lane) * 8];
        f32x4 acc[4] = {z, z, z, z};
        #pragma unroll
        for (int kc8 = 0; kc8 < 8; kc8++) {
            #pragma unroll
            for (int f = 0; f < 4; f++) {
                s16x8 bf = *(const s16x8*)&wb[((((rt & 1) * 4 + f) * 8 + kc8) * 64 + lane) * 8];
                acc[f] = mfma32(a8[kc8], bf, acc[f]);
            }
        }
        #pragma unroll
        for (int f = 0; f < 4; f++) {
            const int och = och0 + f * 16 + l15;
            const float bi = bias[och];
            const int h = och >> 4;
            #pragma unroll
            for (int r = 0; r < 4; r++) {
                const int tok = m0 + quad * 4 + r;
                dst[((b * 8 + h) * 3136 + tok) * 16 + l15] = f2bf((acc[f][r] + bi) * qs);
            }
        }
    } else {
        const int h    = rt - 4;
        const int och0 = h * 64 + wave * 16;
        s16x8 a8[8];
        #pragma unroll
        for (int kc8 = 0; kc8 < 8; kc8++)
            a8[kc8] = *(const s16x8*)&wvpk[(((h * 4 + wave) * 8 + kc8) * 64 + lane) * 8];
        f32x4 acc[4] = {z, z, z, z};
        #pragma unroll
        for (int kc8 = 0; kc8 < 8; kc8++) {
            #pragma unroll
            for (int f = 0; f < 4; f++) {
                s16x8 bf = *(const s16x8*)&xpk[(((b * 196 + blockIdx.x * 4 + f) * 8 + kc8) * 64 + lane) * 8];
                acc[f] = mfma32(a8[kc8], bf, acc[f]);
            }
        }
        // Packed V write (proven v13): value (d=wave*16+quad*4+r,
        // key=c*64+f*16+l15) -> block (c32=f>>1, dt=wave),
        // lane=(l15>>2)*16+quad*4+r, j=(f&1)*4+(l15&3)
        u16* vdst = &vpk[(((b * 8 + h) * 49 + blockIdx.x) * 8) * 512];
        #pragma unroll
        for (int r = 0; r < 4; r++) {
            const float bi = bv[och0 + quad * 4 + r];
            const int lane_r8 = ((l15 >> 2) * 16 + quad * 4 + r) * 8;
            #pragma unroll
            for (int f = 0; f < 4; f++) {
                const int idx = ((f >> 1) * 4 + wave) * 512 + lane_r8 + (f & 1) * 4 + (l15 & 3);
                vdst[idx] = f2bf(acc[f][r] + bi);
            }
        }
    }
}

// ---------------------------------------------------------------------------
// Flash attention v17 = v15's proven 52.4us schedule (no LDS/barriers,
// 1-wave blocks, qt=2, packed-V 1024B loads, K 512B bursts, A/B register
// prefetch, const 0..49 bounds) + cvt_pk P-pack + setprio around PV MFMA.
// Epilogue writes o PACKED for proj. grid (16 bh, 98 q-pairs), 64 thr.
// ---------------------------------------------------------------------------
__global__ __launch_bounds__(64) void attn_kernel(
    const u16* __restrict__ qws, const u16* __restrict__ kws,
    const u16* __restrict__ vpk, u16* __restrict__ opk)
{
    const int bh   = blockIdx.x;                 // x fastest -> XCD = bh%8
    const int nb   = blockIdx.y * 32;            // 2 q-tiles: nb, nb+16
    const int lane = threadIdx.x;
    const int l15  = lane & 15, quad = lane >> 4;

    // Q fragments (B-op): B[k=d=quad*8+j][n=query=l15]; zero for d>=16
    s16x8 aq[2];
    #pragma unroll
    for (int u = 0; u < 2; u++) {
        aq[u] = (s16x8){0, 0, 0, 0, 0, 0, 0, 0};
        if (quad < 2)
            aq[u] = *(const s16x8*)&qws[(bh * 3136 + nb + u * 16 + l15) * 16 + quad * 8];
    }
    s16x8 ones;
    #pragma unroll
    for (int i = 0; i < 8; i++) ones[i] = (short)0x3F80;   // bf16 1.0

    // K frag: A[m=key=l15][k=quad*8+j]; quads 2,3 duplicate 0,1 (B=0 there)
    const u16* krow = &kws[(bh * 3136 + l15) * 16 + (quad & 1) * 8];
    const u16* vb   = &vpk[bh * 49 * 4096 + lane * 8];

    f32x4 acc[2][4], acc5[2];
    #pragma unroll
    for (int u = 0; u < 2; u++) {
        #pragma unroll
        for (int dt = 0; dt < 4; dt++) acc[u][dt] = (f32x4){0.f, 0.f, 0.f, 0.f};
        acc5[u] = (f32x4){0.f, 0.f, 0.f, 0.f};
    }
    const f32x4 z = {0.f, 0.f, 0.f, 0.f};

    s16x8 kfA[4], vfA[8], kfB[4], vfB[8];
    auto loadK = [&](s16x8* kf, int c) {
        #pragma unroll
        for (int ii = 0; ii < 4; ii++)
            kf[ii] = *(const s16x8*)&krow[(c * 64 + ii * 16) * 16];
    };
    auto loadV = [&](s16x8* vf, int c) {
        #pragma unroll
        for (int i = 0; i < 8; i++)
            vf[i] = *(const s16x8*)&vb[(c * 8 + i) * 512];
    };
    auto compute = [&](const s16x8* kf, const s16x8* vf) {
        #pragma unroll
        for (int u = 0; u < 2; u++) {
            f32x4 s[4];
            #pragma unroll
            for (int ii = 0; ii < 4; ii++) s[ii] = mfma32(kf[ii], aq[u], z);
            // exp2 then pack pairs with v_cvt_pk_bf16_f32 (proven v16):
            // pf[c32] words: w0=pk(e[2c32][0],[1]) w1=pk(e[2c32][2],[3])
            //                w2=pk(e[2c32+1][0],[1]) w3=pk(e[2c32+1][2],[3])
            float e[4][4];
            #pragma unroll
            for (int ii = 0; ii < 4; ii++)
                #pragma unroll
                for (int r = 0; r < 4; r++)
                    e[ii][r] = __builtin_amdgcn_exp2f(s[ii][r]);
            s16x8 pf[2];
            #pragma unroll
            for (int c32 = 0; c32 < 2; c32++) {
                i32x4 pk;
                pk[0] = cvtpk(e[2 * c32][0],     e[2 * c32][1]);
                pk[1] = cvtpk(e[2 * c32][2],     e[2 * c32][3]);
                pk[2] = cvtpk(e[2 * c32 + 1][0], e[2 * c32 + 1][1]);
                pk[3] = cvtpk(e[2 * c32 + 1][2], e[2 * c32 + 1][3]);
                pf[c32] = __builtin_bit_cast(s16x8, pk);
            }
            __builtin_amdgcn_s_setprio(1);
            #pragma unroll
            for (int c32 = 0; c32 < 2; c32++) {
                #pragma unroll
                for (int dt = 0; dt < 4; dt++)
                    acc[u][dt] = mfma32(vf[c32 * 4 + dt], pf[c32], acc[u][dt]);
                acc5[u] = mfma32(ones, pf[c32], acc5[u]);
            }
            __builtin_amdgcn_s_setprio(0);
        }
    };

    loadK(kfA, 0); loadV(vfA, 0);
    #pragma unroll 1
    for (int c = 0; c < 49; c += 2) {
        if (c + 1 < 49) { loadK(kfB, c + 1); loadV(vfB, c + 1); }
        compute(kfA, vfA);
        if (c + 2 < 49) { loadK(kfA, c + 2); loadV(vfA, c + 2); }
        if (c + 1 < 49) compute(kfB, vfB);
    }

    // ---- epilogue: write o PACKED for proj (vectorized).
    // value (tok = nb+u*16+l15, ch = h*64 + dt*16 + quad*4 + r) lands at
    // opk[((bq*196+tt)*16 + h*2+(dt>>1))*512
    //     + (((dt&1)*2+(quad>>1))*16 + l15)*8 + (quad&1)*4 + r]
    const int bq_ = bh >> 3, h = bh & 7;
    #pragma unroll
    for (int u = 0; u < 2; u++) {
        const float inv = 1.0f / acc5[u][0];     // rowsum for query l15
        const int tt = blockIdx.y * 2 + u;
        u16* ob = &opk[((bq_ * 196 + tt) * 16) * 512];
        #pragma unroll
        for (int dt = 0; dt < 4; dt++) {
            u16x4 o4;
            #pragma unroll
            for (int r = 0; r < 4; r++) o4[r] = f2bf(acc[u][dt][r] * inv);
            *(u16x4*)&ob[(h * 2 + (dt >> 1)) * 512 +
                         (((dt & 1) * 2 + (quad >> 1)) * 16 + l15) * 8 +
                         (quad & 1) * 4] = o4;
        }
    }
}

// ---------------------------------------------------------------------------
// Output projection: ALL loads coalesced from packed layouts. grid (98,4,2).
// A = wppk [256][512] packed, B = opk; C[och][token] -> fp32 out.
// ---------------------------------------------------------------------------
__global__ __launch_bounds__(256, 4) void proj_kernel(
    const u16* __restrict__ opk, const u16* __restrict__ wppk,
    const float* __restrict__ bp, float* __restrict__ out)
{
    const int b = blockIdx.z, n0 = blockIdx.x * 32;
    const int och0 = blockIdx.y * 64 + (threadIdx.x >> 6) * 16;
    const int lane = threadIdx.x & 63;
    const int l15 = lane & 15, quad = lane >> 4;
    const f32x4 z = {0.f, 0.f, 0.f, 0.f};

    const int och_t = blockIdx.y * 4 + (threadIdx.x >> 6);
    s16x8 a8[16];
    #pragma unroll
    for (int kc = 0; kc < 16; kc++)
        a8[kc] = *(const s16x8*)&wppk[((och_t * 16 + kc) * 64 + lane) * 8];
    f32x4 acc[2] = {z, z};
    #pragma unroll
    for (int kc = 0; kc < 16; kc++) {
        #pragma unroll
        for (int f = 0; f < 2; f++) {
            s16x8 bf = *(const s16x8*)&opk[(((b * 196 + blockIdx.x * 2 + f) * 16 + kc) * 64 + lane) * 8];
            acc[f] = mfma32(a8[kc], bf, acc[f]);
        }
    }
    #pragma unroll
    for (int r = 0; r < 4; r++) {
        const int och = och0 + quad * 4 + r;
        const float bi = bp[och];
        #pragma unroll
        for (int f = 0; f < 2; f++)
            out[(b * 256 + och) * 3136 + n0 + f * 16 + l15] = acc[f][r] + bi;
    }
}

// ---------------------------------------------------------------------------
extern "C" void kernel_launch(void* const* d_in, const int* in_sizes, int n_in,
                              void* d_out, int out_size, void* d_ws, size_t ws_size,
                              hipStream_t stream) {
    const float* x  = (const float*)d_in[0];
    const float* wq = (const float*)d_in[1];
    const float* sq = (const float*)d_in[2];
    const float* bq = (const float*)d_in[3];
    const float* wk = (const float*)d_in[4];
    const float* sk = (const float*)d_in[5];
    const float* bk = (const float*)d_in[6];
    const float* wv = (const float*)d_in[7];
    const float* sv = (const float*)d_in[8];
    const float* bv = (const float*)d_in[9];
    const float* wp = (const float*)d_in[10];
    const float* sp = (const float*)d_in[11];
    const float* bp = (const float*)d_in[12];
    float* out = (float*)d_out;

    u16* qws  = (u16*)d_ws;                // 802816
    u16* kws  = qws + 802816;              // 802816
    u16* vpk  = kws + 802816;              // 3211264 (packed V)
    u16* R    = vpk + 3211264;             // 3211264 (xpk then opk, overlaid)
    u16* xpk  = R;
    u16* opk  = R;
    u16* wqpk = R + 3211264;               // 32768
    u16* wkpk = wqpk + 32768;              // 32768
    u16* wvpk = wkpk + 32768;              // 131072
    u16* wppk = wvpk + 131072;             // 131072  (total 16,711,680 B)

    xtw_kernel<<<dim3(49, 4, 3), 256, 0, stream>>>(x, xpk, wq, sq, wk, sk,
                                                   wv, sv, wp, sp,
                                                   wqpk, wkpk, wvpk, wppk);
    qkv_kernel<<<dim3(49, 12, 2), 256, 0, stream>>>(xpk, wqpk, wkpk, wvpk,
                                                    bq, bk, bv, qws, kws, vpk);
    attn_kernel<<<dim3(16, 98), 64, 0, stream>>>(qws, kws, vpk, opk);
    proj_kernel<<<dim3(98, 4, 2), 256, 0, stream>>>(opk, wppk, bp, out);
}